// Round 4
// baseline (423.777 us; speedup 1.0000x reference)
//
#include <hip/hip_runtime.h>
#include <hip/hip_bf16.h>
#include <math.h>

#define EPSF 1e-7f
#define MAXT 0.99999f   // 1 - 1e-5

typedef __attribute__((ext_vector_type(8))) short short8v;   // 8 x bf16 (4 VGPR)
typedef __attribute__((ext_vector_type(4))) float f32x4;     // MFMA C/D frag

constexpr int Bb = 2048;
constexpr int Ss = 768;
constexpr int Dd = 128;
constexpr int Nn = 100000;
constexpr int Kk = 5;
constexpr int HALF = Bb * Dd;        // 262144
constexpr int RT = 128;              // rows per topk block
constexpr int NT = 128;              // nodes per tile

// fast path (pre-packed bf16): 32 chunks of 3125 real nodes, padded to 3200
constexpr int NCH32 = 32;
constexpr int CH32 = Nn / NCH32;     // 3125 (exact)
constexpr int TIL32 = 25;            // tiles per chunk (25*128 = 3200)
constexpr int PADC = TIL32 * NT;     // 3200 padded nodes per chunk
constexpr int TILE_BYTES = NT * Dd * 2;  // 32768

// legacy path (round-3, verified): 16 chunks of 6250
constexpr int NCH16 = 16;
constexpr int CH16 = Nn / NCH16;     // 6250
constexpr int TIL16 = (CH16 + NT - 1) / NT;  // 49

static __device__ __forceinline__ ushort f2bf(float x) {
  __hip_bfloat16 h = __float2bfloat16(x);
  return *reinterpret_cast<ushort*>(&h);
}

// Insert into ascending-sorted top-5 (strict <: keeps earliest/lowest idx on tie).
#define INS5(TV, TI, V, ID) do { \
  const float _v = (V); const int _id = (ID); \
  if (_v < TV[4]) { \
    TV[4] = _v; TI[4] = _id; \
    if (TV[4] < TV[3]) { float _t=TV[3];TV[3]=TV[4];TV[4]=_t;int _u=TI[3];TI[3]=TI[4];TI[4]=_u; } \
    if (TV[3] < TV[2]) { float _t=TV[2];TV[2]=TV[3];TV[3]=_t;int _u=TI[2];TI[2]=TI[3];TI[3]=_u; } \
    if (TV[2] < TV[1]) { float _t=TV[1];TV[1]=TV[2];TV[2]=_t;int _u=TI[1];TI[1]=TI[2];TI[2]=_u; } \
    if (TV[1] < TV[0]) { float _t=TV[0];TV[0]=TV[1];TV[1]=_t;int _u=TI[0];TI[0]=TI[1];TI[1]=_u; } \
  } } while(0)

// Lexicographic (value, index) insert for merging unordered candidate streams.
#define LXLT(V,I,V2,I2) ((V) < (V2) || ((V) == (V2) && (I) < (I2)))
#define INS5L(TV, TI, V, ID) do { \
  const float _v = (V); const int _id = (ID); \
  if (LXLT(_v,_id,TV[4],TI[4])) { \
    TV[4]=_v; TI[4]=_id; \
    if (LXLT(TV[4],TI[4],TV[3],TI[3])) { float _t=TV[3];TV[3]=TV[4];TV[4]=_t;int _u=TI[3];TI[3]=TI[4];TI[4]=_u; } \
    if (LXLT(TV[3],TI[3],TV[2],TI[2])) { float _t=TV[2];TV[2]=TV[3];TV[3]=_t;int _u=TI[2];TI[2]=TI[3];TI[3]=_u; } \
    if (LXLT(TV[2],TI[2],TV[1],TI[1])) { float _t=TV[1];TV[1]=TV[2];TV[2]=_t;int _u=TI[1];TI[1]=TI[2];TI[2]=_u; } \
    if (LXLT(TV[1],TI[1],TV[0],TI[0])) { float _t=TV[0];TV[0]=TV[1];TV[1]=_t;int _u=TI[0];TI[0]=TI[1];TI[1]=_u; } \
  } } while(0)

// ---------------------------------------------------------------------------
// Kernel 1 (shared): z_proj = z_seq @ W.T + b; z_hyp = expmap0 -> out[HALF..];
// z_tan = logmap0(z_hyp) -> ztb (bf16). 8 rows/block, 128 threads.
__global__ __launch_bounds__(128) void k_proj(
    const float* __restrict__ zseq, const float* __restrict__ W,
    const float* __restrict__ bias, float* __restrict__ outH,
    ushort* __restrict__ ztb)
{
  __shared__ __align__(16) float zrow[8][768];
  __shared__ float zp[8][128];
  __shared__ float rno[8];
  const int tid = threadIdx.x;
  const int r0 = blockIdx.x * 8;

  {
    const float4* src = reinterpret_cast<const float4*>(zseq + (size_t)r0 * Ss);
    float4* dst = reinterpret_cast<float4*>(&zrow[0][0]);
    #pragma unroll
    for (int i = 0; i < 12; ++i) dst[i * 128 + tid] = src[i * 128 + tid];
  }
  __syncthreads();

  float acc[8];
  const float bv = bias[tid];
  #pragma unroll
  for (int r = 0; r < 8; ++r) acc[r] = bv;
  const float4* w4 = reinterpret_cast<const float4*>(W + (size_t)tid * Ss);
  for (int j = 0; j < Ss / 4; ++j) {
    const float4 w = w4[j];
    #pragma unroll
    for (int r = 0; r < 8; ++r) {
      const float4 z = *reinterpret_cast<const float4*>(&zrow[r][j * 4]);
      acc[r] = fmaf(z.x, w.x, acc[r]);
      acc[r] = fmaf(z.y, w.y, acc[r]);
      acc[r] = fmaf(z.z, w.z, acc[r]);
      acc[r] = fmaf(z.w, w.w, acc[r]);
    }
  }
  #pragma unroll
  for (int r = 0; r < 8; ++r) zp[r][tid] = acc[r];
  __syncthreads();

  const int wv = tid >> 6, ln = tid & 63;
  #pragma unroll
  for (int rr = 0; rr < 4; ++rr) {
    const int r = wv * 4 + rr;
    float v = zp[r][ln] * zp[r][ln] + zp[r][ln + 64] * zp[r][ln + 64];
    #pragma unroll
    for (int off = 32; off > 0; off >>= 1) v += __shfl_xor(v, off);
    if (ln == 0) rno[r] = v;
  }
  __syncthreads();

  #pragma unroll
  for (int r = 0; r < 8; ++r) {
    const float n = fmaxf(sqrtf(rno[r]), EPSF);
    const float zh = tanhf(n) * zp[r][tid] / n;
    outH[(size_t)(r0 + r) * Dd + tid] = zh;   // z_hyp output (f32)
    zp[r][tid] = zh;
  }
  __syncthreads();
  #pragma unroll
  for (int rr = 0; rr < 4; ++rr) {
    const int r = wv * 4 + rr;
    float v = zp[r][ln] * zp[r][ln] + zp[r][ln + 64] * zp[r][ln + 64];
    #pragma unroll
    for (int off = 32; off > 0; off >>= 1) v += __shfl_xor(v, off);
    if (ln == 0) rno[r] = v;
  }
  __syncthreads();
  #pragma unroll
  for (int r = 0; r < 8; ++r) {
    const float m = fmaxf(sqrtf(rno[r]), EPSF);
    const float a = atanhf(fminf(m, MAXT));
    ztb[(size_t)(r0 + r) * Dd + tid] = f2bf(a * zp[r][tid] / m);
  }
}

// ---------------------------------------------------------------------------
// FAST PATH kernel: pre-pack emb into pre-swizzled bf16 LDS image + scl=(-2s,c).
// One wave per padded node (102400 total), 4 nodes/block.
__global__ __launch_bounds__(256) void k_pack(
    const float* __restrict__ emb, ushort* __restrict__ embsw,
    float2* __restrict__ scl)
{
  const int wv = threadIdx.x >> 6, ln = threadIdx.x & 63;
  const int p = blockIdx.x * 4 + wv;          // padded index
  const int chunk = p / PADC;
  const int local = p - chunk * PADC;
  const bool real = local < CH32;
  const int node = chunk * CH32 + local;
  float2 v = make_float2(0.f, 0.f);
  if (real) v = *reinterpret_cast<const float2*>(emb + (size_t)node * Dd + ln * 2);
  float t = v.x * v.x + v.y * v.y;
  #pragma unroll
  for (int off = 32; off > 0; off >>= 1) t += __shfl_xor(t, off);

  const int tt = local >> 7, nd = local & 127;
  ushort2 w; w.x = f2bf(v.x); w.y = f2bf(v.y);
  char* dst = reinterpret_cast<char*>(embsw)
            + ((size_t)((chunk * TIL32 + tt) * NT + nd) << 8)
            + ((ln * 4) ^ ((nd & 7) << 4));
  *reinterpret_cast<ushort2*>(dst) = w;

  if (ln == 0) {
    float2 sc;
    if (real) {
      const float E = fmaxf(sqrtf(t), EPSF);
      const float a = atanhf(fminf(E, MAXT));
      const float s = a / E;
      sc = make_float2(-2.f * s, s * s * t);
    } else {
      sc = make_float2(0.f, 3.0e38f);
    }
    scl[p] = sc;
  }
}

// ---------------------------------------------------------------------------
// FAST PATH kernel 3: bf16-MFMA score GEMM + fused top-5, zero-VALU staging.
// Block = 128 rows x 3125-node chunk; 8 waves = 4 row-groups x 2 col-groups.
__global__ __launch_bounds__(512, 2) void k_topk32(
    const ushort* __restrict__ ztb, const ushort* __restrict__ embsw,
    const float2* __restrict__ scl, float* __restrict__ candV,
    int* __restrict__ candI)
{
  __shared__ __align__(16) ushort Bsm[2][NT * Dd];   // 2 x 32KB, swizzled image
  __shared__ __align__(16) float2 sclb[2][NT];       // (-2s, c)

  const int tid = threadIdx.x;
  const int ln = tid & 63;
  const int wv = tid >> 6;       // 0..7
  const int ln15 = ln & 15;
  const int g = ln >> 4;         // 0..3
  const int wr = wv >> 1;        // row-group 0..3 (32 rows each)
  const int wc = wv & 1;         // col-group 0..1 (64 cols each)
  const int rowBase = blockIdx.x * RT;
  const int chunk = blockIdx.y;
  const char* embc = reinterpret_cast<const char*>(embsw)
                   + (size_t)chunk * (TIL32 * TILE_BYTES);
  const float2* sclc = scl + chunk * PADC;

  // A fragments in registers, reused across all 25 tiles
  short8v afr[2][4];
  #pragma unroll
  for (int f = 0; f < 2; ++f)
    #pragma unroll
    for (int ks = 0; ks < 4; ++ks)
      afr[f][ks] = *reinterpret_cast<const short8v*>(
          ztb + (size_t)(rowBase + 32 * wr + 16 * f + ln15) * Dd + 32 * ks + 8 * g);

  // per-lane swizzled LDS byte offsets for B-frag reads (+ c*4096 immediate)
  int rdoff[4];
  #pragma unroll
  for (int ks = 0; ks < 4; ++ks)
    rdoff[ks] = (wc * 64 + ln15) * 256 + ((g * 16 + ks * 64) ^ ((ln15 & 7) << 4));

  float tv[8][5]; int ti[8][5];
  #pragma unroll
  for (int r = 0; r < 8; ++r)
    #pragma unroll
    for (int q = 0; q < 5; ++q) { tv[r][q] = 3.0e38f; ti[r][q] = 0x7fffffff; }

  auto stage = [&](int t, int buf) {
    const char* src = embc + (size_t)t * TILE_BYTES + tid * 16;
    char* lb = reinterpret_cast<char*>(&Bsm[buf][0]) + tid * 16;
    #pragma unroll
    for (int i = 0; i < 4; ++i) {
      __builtin_amdgcn_global_load_lds(
          (const __attribute__((address_space(1))) unsigned int*)(src + i * 8192),
          (__attribute__((address_space(3))) unsigned int*)(lb + i * 8192),
          16, 0, 0);
    }
    if (tid < NT) sclb[buf][tid] = sclc[t * NT + tid];
  };

  stage(0, 0);
  __syncthreads();

  for (int t = 0; t < TIL32; ++t) {
    const int buf = t & 1;
    if (t + 1 < TIL32) stage(t + 1, buf ^ 1);   // prefetch, drained at barrier

    const char* bbase = reinterpret_cast<const char*>(&Bsm[buf][0]);
    f32x4 acc[2][4];
    #pragma unroll
    for (int c = 0; c < 4; ++c) {
      {
        const short8v bfr = *reinterpret_cast<const short8v*>(bbase + c * 4096 + rdoff[0]);
        acc[0][c] = __builtin_amdgcn_mfma_f32_16x16x32_bf16(afr[0][0], bfr, (f32x4)0.f, 0, 0, 0);
        acc[1][c] = __builtin_amdgcn_mfma_f32_16x16x32_bf16(afr[1][0], bfr, (f32x4)0.f, 0, 0, 0);
      }
      #pragma unroll
      for (int ks = 1; ks < 4; ++ks) {
        const short8v bfr = *reinterpret_cast<const short8v*>(bbase + c * 4096 + rdoff[ks]);
        acc[0][c] = __builtin_amdgcn_mfma_f32_16x16x32_bf16(afr[0][ks], bfr, acc[0][c], 0, 0, 0);
        acc[1][c] = __builtin_amdgcn_mfma_f32_16x16x32_bf16(afr[1][ks], bfr, acc[1][c], 0, 0, 0);
      }
    }

    // epilogue: scores + per-lane top-5 (8 rows/lane, 4 nodes each)
    #pragma unroll
    for (int c = 0; c < 4; ++c) {
      const int nl = wc * 64 + c * 16 + ln15;
      const float2 sc2 = sclb[buf][nl];        // (-2s, c)
      const int node = chunk * CH32 + t * NT + nl;  // pad scores are +INF, never win
      #pragma unroll
      for (int f = 0; f < 2; ++f)
        #pragma unroll
        for (int i = 0; i < 4; ++i) {
          const float v = fmaf(sc2.x, acc[f][c][i], sc2.y);
          INS5(tv[f * 4 + i], ti[f * 4 + i], v, node);
        }
    }
    __syncthreads();
  }

  // butterfly merge across the 16 lanes sharing each row set
  #pragma unroll
  for (int m = 1; m <= 8; m <<= 1) {
    #pragma unroll
    for (int r = 0; r < 8; ++r) {
      float ov[5]; int oi[5];
      #pragma unroll
      for (int q = 0; q < 5; ++q) {
        ov[q] = __shfl_xor(tv[r][q], m);
        oi[q] = __shfl_xor(ti[r][q], m);
      }
      #pragma unroll
      for (int q = 0; q < 5; ++q) INS5L(tv[r], ti[r], ov[q], oi[q]);
    }
  }
  // cross-wave merge via reused Bsm LDS (safe: loop-end barrier passed)
  float* mgv = reinterpret_cast<float*>(&Bsm[0][0]);             // [RT][2][5]
  int* mgi = reinterpret_cast<int*>(
      reinterpret_cast<char*>(&Bsm[0][0]) + RT * 2 * Kk * 4);
  if (ln15 == 0) {
    #pragma unroll
    for (int f = 0; f < 2; ++f)
      #pragma unroll
      for (int i = 0; i < 4; ++i) {
        const int row = 32 * wr + 16 * f + 4 * g + i;
        #pragma unroll
        for (int q = 0; q < 5; ++q) {
          mgv[(row * 2 + wc) * Kk + q] = tv[f * 4 + i][q];
          mgi[(row * 2 + wc) * Kk + q] = ti[f * 4 + i][q];
        }
      }
  }
  __syncthreads();
  if (tid < RT) {
    float mv[5]; int mi[5];
    #pragma unroll
    for (int q = 0; q < 5; ++q) { mv[q] = mgv[(tid * 2 + 0) * Kk + q]; mi[q] = mgi[(tid * 2 + 0) * Kk + q]; }
    #pragma unroll
    for (int q = 0; q < 5; ++q) INS5L(mv, mi, mgv[(tid * 2 + 1) * Kk + q], mgi[(tid * 2 + 1) * Kk + q]);
    const size_t o = ((size_t)(rowBase + tid) * NCH32 + chunk) * Kk;
    #pragma unroll
    for (int q = 0; q < 5; ++q) { candV[o + q] = mv[q]; candI[o + q] = mi[q]; }
  }
}

// ---------------------------------------------------------------------------
// LEGACY PATH (round-3, verified): per-node scalars + in-loop cvt staging.
__global__ __launch_bounds__(256) void k_node(
    const float* __restrict__ emb, float* __restrict__ sArr, float* __restrict__ cArr)
{
  const int wv = threadIdx.x >> 6, ln = threadIdx.x & 63;
  const int node = blockIdx.x * 4 + wv;
  const float2 v = *reinterpret_cast<const float2*>(emb + (size_t)node * Dd + ln * 2);
  float t = v.x * v.x + v.y * v.y;
  #pragma unroll
  for (int off = 32; off > 0; off >>= 1) t += __shfl_xor(t, off);
  if (ln == 0) {
    const float E = fmaxf(sqrtf(t), EPSF);
    const float a = atanhf(fminf(E, MAXT));
    const float s = a / E;
    sArr[node] = s;
    cArr[node] = s * s * t;
  }
}

__global__ __launch_bounds__(512, 2) void k_topk16(
    const ushort* __restrict__ ztb, const float* __restrict__ emb,
    const float* __restrict__ sArr, const float* __restrict__ cArr,
    float* __restrict__ candV, int* __restrict__ candI)
{
  __shared__ __align__(16) ushort Bsm[2][NT * Dd];
  __shared__ __align__(16) float2 sclb[2][NT];
  __shared__ __align__(16) float mgv[RT][2][Kk];
  __shared__ int mgi[RT][2][Kk];

  const int tid = threadIdx.x;
  const int ln = tid & 63;
  const int wv = tid >> 6;
  const int ln15 = ln & 15;
  const int g = ln >> 4;
  const int wr = wv >> 1;
  const int wc = wv & 1;
  const int rowBase = blockIdx.x * RT;
  const int chunkStart = blockIdx.y * CH16;

  short8v afr[2][4];
  #pragma unroll
  for (int f = 0; f < 2; ++f)
    #pragma unroll
    for (int ks = 0; ks < 4; ++ks)
      afr[f][ks] = *reinterpret_cast<const short8v*>(
          ztb + (size_t)(rowBase + 32 * wr + 16 * f + ln15) * Dd + 32 * ks + 8 * g);

  int rdoff[4];
  #pragma unroll
  for (int ks = 0; ks < 4; ++ks)
    rdoff[ks] = (wc * 64 + ln15) * 256 + ((g * 16 + ks * 64) ^ ((ln15 & 7) << 4));

  f32x4 acc[2][4];
  #pragma unroll
  for (int f = 0; f < 2; ++f)
    #pragma unroll
    for (int c = 0; c < 4; ++c) acc[f][c] = (f32x4)0.f;

  float tv[8][5]; int ti[8][5];
  #pragma unroll
  for (int r = 0; r < 8; ++r)
    #pragma unroll
    for (int q = 0; q < 5; ++q) { tv[r][q] = 3.0e38f; ti[r][q] = 0x7fffffff; }

  float4 ld[8];

  auto stageLoad = [&](int t) {
    const int tStart = t * NT;
    const int left = CH16 - tStart;
    #pragma unroll
    for (int i = 0; i < 8; ++i) {
      const int flat = i * 512 + tid;
      const int nd = flat >> 5;
      float4 v = make_float4(0.f, 0.f, 0.f, 0.f);
      if (nd < left)
        v = *reinterpret_cast<const float4*>(
            emb + (size_t)(chunkStart + tStart + nd) * Dd + (flat & 31) * 4);
      ld[i] = v;
    }
  };

  auto stageWrite = [&](int t, int buf) {
    char* base = reinterpret_cast<char*>(&Bsm[buf][0]);
    #pragma unroll
    for (int i = 0; i < 8; ++i) {
      const int flat = i * 512 + tid;
      const int nd = flat >> 5;
      const int kb = (flat & 31) * 8;
      ushort4 w;
      w.x = f2bf(ld[i].x); w.y = f2bf(ld[i].y);
      w.z = f2bf(ld[i].z); w.w = f2bf(ld[i].w);
      *reinterpret_cast<ushort4*>(base + nd * 256 + (kb ^ ((nd & 7) << 4))) = w;
    }
    const int tStart = t * NT;
    const int left = CH16 - tStart;
    if (tid < NT) {
      const bool ok = tid < left;
      sclb[buf][tid] = make_float2(ok ? -2.f * sArr[chunkStart + tStart + tid] : 0.f,
                                   ok ? cArr[chunkStart + tStart + tid] : 3.0e38f);
    }
  };

  stageLoad(0);
  stageWrite(0, 0);
  __syncthreads();

  for (int t = 0; t < TIL16; ++t) {
    const int buf = t & 1;
    const bool have = (t + 1) < TIL16;
    if (have) stageLoad(t + 1);

    const char* bbase = reinterpret_cast<const char*>(&Bsm[buf][0]);
    #pragma unroll
    for (int c = 0; c < 4; ++c) {
      #pragma unroll
      for (int ks = 0; ks < 4; ++ks) {
        const short8v bfr = *reinterpret_cast<const short8v*>(bbase + c * 4096 + rdoff[ks]);
        acc[0][c] = __builtin_amdgcn_mfma_f32_16x16x32_bf16(afr[0][ks], bfr, acc[0][c], 0, 0, 0);
        acc[1][c] = __builtin_amdgcn_mfma_f32_16x16x32_bf16(afr[1][ks], bfr, acc[1][c], 0, 0, 0);
      }
    }

    if (have) stageWrite(t + 1, buf ^ 1);

    #pragma unroll
    for (int c = 0; c < 4; ++c) {
      const int nl = wc * 64 + c * 16 + ln15;
      const float2 sc2 = sclb[buf][nl];
      const int node = chunkStart + t * NT + nl;
      #pragma unroll
      for (int f = 0; f < 2; ++f) {
        #pragma unroll
        for (int i = 0; i < 4; ++i) {
          const float v = fmaf(sc2.x, acc[f][c][i], sc2.y);
          INS5(tv[f * 4 + i], ti[f * 4 + i], v, node);
        }
        acc[f][c] = (f32x4)0.f;
      }
    }
    __syncthreads();
  }

  #pragma unroll
  for (int m = 1; m <= 8; m <<= 1) {
    #pragma unroll
    for (int r = 0; r < 8; ++r) {
      float ov[5]; int oi[5];
      #pragma unroll
      for (int q = 0; q < 5; ++q) {
        ov[q] = __shfl_xor(tv[r][q], m);
        oi[q] = __shfl_xor(ti[r][q], m);
      }
      #pragma unroll
      for (int q = 0; q < 5; ++q) INS5L(tv[r], ti[r], ov[q], oi[q]);
    }
  }
  if (ln15 == 0) {
    #pragma unroll
    for (int f = 0; f < 2; ++f)
      #pragma unroll
      for (int i = 0; i < 4; ++i) {
        const int row = 32 * wr + 16 * f + 4 * g + i;
        #pragma unroll
        for (int q = 0; q < 5; ++q) {
          mgv[row][wc][q] = tv[f * 4 + i][q];
          mgi[row][wc][q] = ti[f * 4 + i][q];
        }
      }
  }
  __syncthreads();
  if (tid < RT) {
    float mv[5]; int mi[5];
    #pragma unroll
    for (int q = 0; q < 5; ++q) { mv[q] = mgv[tid][0][q]; mi[q] = mgi[tid][0][q]; }
    #pragma unroll
    for (int q = 0; q < 5; ++q) INS5L(mv, mi, mgv[tid][1][q], mgi[tid][1][q]);
    const size_t o = ((size_t)(rowBase + tid) * NCH16 + blockIdx.y) * Kk;
    #pragma unroll
    for (int q = 0; q < 5; ++q) { candV[o + q] = mv[q]; candI[o + q] = mi[q]; }
  }
}

// ---------------------------------------------------------------------------
// Kernel 4 (shared): wave-parallel final merge -> gather-mean -> mobius_add.
__global__ __launch_bounds__(128) void k_fuse(
    const float* __restrict__ emb, const float* __restrict__ candV,
    const int* __restrict__ candI, const float* __restrict__ zhyp,
    float* __restrict__ out, int ncand)
{
  __shared__ int sidx[Kk];
  __shared__ float red[6];
  const int row = blockIdx.x;
  const int tid = threadIdx.x;
  if (tid < 64) {
    float mv[5]; int mi[5];
    #pragma unroll
    for (int q = 0; q < 5; ++q) { mv[q] = 3.0e38f; mi[q] = 0x7fffffff; }
    const size_t base = (size_t)row * ncand;
    for (int j = tid; j < ncand; j += 64) INS5L(mv, mi, candV[base + j], candI[base + j]);
    #pragma unroll
    for (int m = 1; m <= 32; m <<= 1) {
      float ov[5]; int oi[5];
      #pragma unroll
      for (int q = 0; q < 5; ++q) { ov[q] = __shfl_xor(mv[q], m); oi[q] = __shfl_xor(mi[q], m); }
      #pragma unroll
      for (int q = 0; q < 5; ++q) INS5L(mv, mi, ov[q], oi[q]);
    }
    if (tid == 0) {
      #pragma unroll
      for (int q = 0; q < 5; ++q) sidx[q] = mi[q];
    }
  }
  __syncthreads();
  float y = 0.f;
  #pragma unroll
  for (int q = 0; q < Kk; ++q) y += emb[(size_t)sidx[q] * Dd + tid];
  y = y / 5.0f;
  const float x = zhyp[(size_t)row * Dd + tid];
  float x2 = x * x, y2 = y * y, xy = x * y;
  #pragma unroll
  for (int off = 32; off > 0; off >>= 1) {
    x2 += __shfl_xor(x2, off);
    y2 += __shfl_xor(y2, off);
    xy += __shfl_xor(xy, off);
  }
  const int wv = tid >> 6, ln = tid & 63;
  if (ln == 0) { red[wv * 3 + 0] = x2; red[wv * 3 + 1] = y2; red[wv * 3 + 2] = xy; }
  __syncthreads();
  x2 = red[0] + red[3]; y2 = red[1] + red[4]; xy = red[2] + red[5];
  const float num = (1.f + 2.f * xy + y2) * x + (1.f - x2) * y;
  const float den = 1.f + 2.f * xy + x2 * y2;
  out[(size_t)row * Dd + tid] = num / (den + EPSF);
}

// ---------------------------------------------------------------------------
extern "C" void kernel_launch(void* const* d_in, const int* in_sizes, int n_in,
                              void* d_out, int out_size, void* d_ws, size_t ws_size,
                              hipStream_t stream)
{
  (void)in_sizes; (void)n_in; (void)out_size;
  const float* zseq = (const float*)d_in[0];
  const float* emb  = (const float*)d_in[1];
  const float* W    = (const float*)d_in[2];
  const float* bias = (const float*)d_in[3];
  float* out = (float*)d_out;            // [z_fused (B*D) | z_hyp (B*D)] f32

  const size_t ztbBytes   = (size_t)Bb * Dd * 2;                  // 524288
  const size_t embswBytes = (size_t)NCH32 * TIL32 * TILE_BYTES;   // 26214400
  const size_t sclBytes   = (size_t)NCH32 * PADC * 8;             // 819200
  const size_t candVBytes = (size_t)Bb * NCH32 * Kk * 4;          // 1310720
  const size_t needFast = ztbBytes + embswBytes + sclBytes + 2 * candVBytes;

  hipLaunchKernelGGL(k_proj, dim3(Bb / 8), dim3(128), 0, stream,
                     zseq, W, bias, out + HALF, (ushort*)d_ws);

  if (ws_size >= needFast) {
    char* ws = (char*)d_ws;
    ushort* ztb   = (ushort*)ws;
    ushort* embsw = (ushort*)(ws + ztbBytes);
    float2* scl   = (float2*)(ws + ztbBytes + embswBytes);
    float* candV  = (float*)(ws + ztbBytes + embswBytes + sclBytes);
    int*   candI  = (int*)(ws + ztbBytes + embswBytes + sclBytes + candVBytes);

    hipLaunchKernelGGL(k_pack, dim3(NCH32 * PADC / 4), dim3(256), 0, stream,
                       emb, embsw, scl);
    hipLaunchKernelGGL(k_topk32, dim3(Bb / RT, NCH32), dim3(512), 0, stream,
                       ztb, embsw, scl, candV, candI);
    hipLaunchKernelGGL(k_fuse, dim3(Bb), dim3(128), 0, stream,
                       emb, candV, candI, out + HALF, out, NCH32 * Kk);
  } else {
    char* ws = (char*)d_ws;
    ushort* ztb  = (ushort*)ws;
    float* sArr  = (float*)(ws + ztbBytes);
    float* cArr  = sArr + Nn;
    float* candV = cArr + Nn;
    int*   candI = (int*)(candV + (size_t)Bb * NCH16 * Kk);

    hipLaunchKernelGGL(k_node, dim3(Nn / 4), dim3(256), 0, stream, emb, sArr, cArr);
    hipLaunchKernelGGL(k_topk16, dim3(Bb / RT, NCH16), dim3(512), 0, stream,
                       ztb, emb, sArr, cArr, candV, candI);
    hipLaunchKernelGGL(k_fuse, dim3(Bb), dim3(128), 0, stream,
                       emb, candV, candI, out + HALF, out, NCH16 * Kk);
  }
}

// Round 5
// 298.078 us; speedup vs baseline: 1.4217x; 1.4217x over previous
//
#include <hip/hip_runtime.h>
#include <hip/hip_bf16.h>
#include <math.h>

#define EPSF 1e-7f
#define MAXT 0.99999f   // 1 - 1e-5

typedef __attribute__((ext_vector_type(8))) short short8v;   // 8 x bf16 (4 VGPR)
typedef __attribute__((ext_vector_type(4))) float f32x4;     // MFMA C/D frag

constexpr int Bb = 2048;
constexpr int Ss = 768;
constexpr int Dd = 128;
constexpr int Nn = 100000;
constexpr int Kk = 5;
constexpr int HALF = Bb * Dd;        // 262144
constexpr int NT = 128;              // nodes per tile
constexpr int TILE_BYTES = NT * Dd * 2;  // 32768

// fast path: transposed MFMA (A=emb', B=z), 8 chunks of 12500, 98 tiles/chunk
constexpr int NCH8 = 8;
constexpr int CH8 = Nn / NCH8;       // 12500
constexpr int TIL8 = 98;             // ceil(12500/128)
constexpr int PAD8 = TIL8 * NT;      // 12544 padded slots per chunk
constexpr int RQ = 32;               // query rows per block

// legacy path (round-3, verified): 16 chunks of 6250, in-loop cvt staging
constexpr int NCH16 = 16;
constexpr int CH16 = Nn / NCH16;     // 6250
constexpr int TIL16 = (CH16 + NT - 1) / NT;  // 49
constexpr int RT = 128;

static __device__ __forceinline__ ushort f2bf(float x) {
  __hip_bfloat16 h = __float2bfloat16(x);
  return *reinterpret_cast<ushort*>(&h);
}

// Insert into ascending-sorted top-5 (strict <: keeps earliest/lowest idx on tie).
#define INS5(TV, TI, V, ID) do { \
  const float _v = (V); const int _id = (ID); \
  if (_v < TV[4]) { \
    TV[4] = _v; TI[4] = _id; \
    if (TV[4] < TV[3]) { float _t=TV[3];TV[3]=TV[4];TV[4]=_t;int _u=TI[3];TI[3]=TI[4];TI[4]=_u; } \
    if (TV[3] < TV[2]) { float _t=TV[2];TV[2]=TV[3];TV[3]=_t;int _u=TI[2];TI[2]=TI[3];TI[3]=_u; } \
    if (TV[2] < TV[1]) { float _t=TV[1];TV[1]=TV[2];TV[2]=_t;int _u=TI[1];TI[1]=TI[2];TI[2]=_u; } \
    if (TV[1] < TV[0]) { float _t=TV[0];TV[0]=TV[1];TV[1]=_t;int _u=TI[0];TI[0]=TI[1];TI[1]=_u; } \
  } } while(0)

// Lexicographic (value, index) insert for merging unordered candidate streams.
#define LXLT(V,I,V2,I2) ((V) < (V2) || ((V) == (V2) && (I) < (I2)))
#define INS5L(TV, TI, V, ID) do { \
  const float _v = (V); const int _id = (ID); \
  if (LXLT(_v,_id,TV[4],TI[4])) { \
    TV[4]=_v; TI[4]=_id; \
    if (LXLT(TV[4],TI[4],TV[3],TI[3])) { float _t=TV[3];TV[3]=TV[4];TV[4]=_t;int _u=TI[3];TI[3]=TI[4];TI[4]=_u; } \
    if (LXLT(TV[3],TI[3],TV[2],TI[2])) { float _t=TV[2];TV[2]=TV[3];TV[3]=_t;int _u=TI[2];TI[2]=TI[3];TI[3]=_u; } \
    if (LXLT(TV[2],TI[2],TV[1],TI[1])) { float _t=TV[1];TV[1]=TV[2];TV[2]=_t;int _u=TI[1];TI[1]=TI[2];TI[2]=_u; } \
    if (LXLT(TV[1],TI[1],TV[0],TI[0])) { float _t=TV[0];TV[0]=TV[1];TV[1]=_t;int _u=TI[0];TI[0]=TI[1];TI[1]=_u; } \
  } } while(0)

// ---------------------------------------------------------------------------
// Kernel 1 (shared): z_proj = z_seq @ W.T + b; z_hyp = expmap0 -> out[HALF..];
// z_tan = logmap0(z_hyp) -> ztb (bf16). 8 rows/block, 128 threads.
__global__ __launch_bounds__(128) void k_proj(
    const float* __restrict__ zseq, const float* __restrict__ W,
    const float* __restrict__ bias, float* __restrict__ outH,
    ushort* __restrict__ ztb)
{
  __shared__ __align__(16) float zrow[8][768];
  __shared__ float zp[8][128];
  __shared__ float rno[8];
  const int tid = threadIdx.x;
  const int r0 = blockIdx.x * 8;

  {
    const float4* src = reinterpret_cast<const float4*>(zseq + (size_t)r0 * Ss);
    float4* dst = reinterpret_cast<float4*>(&zrow[0][0]);
    #pragma unroll
    for (int i = 0; i < 12; ++i) dst[i * 128 + tid] = src[i * 128 + tid];
  }
  __syncthreads();

  float acc[8];
  const float bv = bias[tid];
  #pragma unroll
  for (int r = 0; r < 8; ++r) acc[r] = bv;
  const float4* w4 = reinterpret_cast<const float4*>(W + (size_t)tid * Ss);
  for (int j = 0; j < Ss / 4; ++j) {
    const float4 w = w4[j];
    #pragma unroll
    for (int r = 0; r < 8; ++r) {
      const float4 z = *reinterpret_cast<const float4*>(&zrow[r][j * 4]);
      acc[r] = fmaf(z.x, w.x, acc[r]);
      acc[r] = fmaf(z.y, w.y, acc[r]);
      acc[r] = fmaf(z.z, w.z, acc[r]);
      acc[r] = fmaf(z.w, w.w, acc[r]);
    }
  }
  #pragma unroll
  for (int r = 0; r < 8; ++r) zp[r][tid] = acc[r];
  __syncthreads();

  const int wv = tid >> 6, ln = tid & 63;
  #pragma unroll
  for (int rr = 0; rr < 4; ++rr) {
    const int r = wv * 4 + rr;
    float v = zp[r][ln] * zp[r][ln] + zp[r][ln + 64] * zp[r][ln + 64];
    #pragma unroll
    for (int off = 32; off > 0; off >>= 1) v += __shfl_xor(v, off);
    if (ln == 0) rno[r] = v;
  }
  __syncthreads();

  #pragma unroll
  for (int r = 0; r < 8; ++r) {
    const float n = fmaxf(sqrtf(rno[r]), EPSF);
    const float zh = tanhf(n) * zp[r][tid] / n;
    outH[(size_t)(r0 + r) * Dd + tid] = zh;   // z_hyp output (f32)
    zp[r][tid] = zh;
  }
  __syncthreads();
  #pragma unroll
  for (int rr = 0; rr < 4; ++rr) {
    const int r = wv * 4 + rr;
    float v = zp[r][ln] * zp[r][ln] + zp[r][ln + 64] * zp[r][ln + 64];
    #pragma unroll
    for (int off = 32; off > 0; off >>= 1) v += __shfl_xor(v, off);
    if (ln == 0) rno[r] = v;
  }
  __syncthreads();
  #pragma unroll
  for (int r = 0; r < 8; ++r) {
    const float m = fmaxf(sqrtf(rno[r]), EPSF);
    const float a = atanhf(fminf(m, MAXT));
    ztb[(size_t)(r0 + r) * Dd + tid] = f2bf(a * zp[r][tid] / m);
  }
}

// ---------------------------------------------------------------------------
// FAST PATH pack: emb' = bf16(-2*s_n*emb_n) pre-swizzled in tiled LDS image;
// cpad[slot] = c_n (or +INF for pad slots). One wave per padded slot.
__global__ __launch_bounds__(256) void k_pack(
    const float* __restrict__ emb, ushort* __restrict__ embsw,
    float* __restrict__ cpad)
{
  const int wv = threadIdx.x >> 6, ln = threadIdx.x & 63;
  const int p = blockIdx.x * 4 + wv;          // padded slot
  const int chunk = p / PAD8;
  const int local = p - chunk * PAD8;
  const bool real = local < CH8;
  const int node = chunk * CH8 + local;
  float2 v = make_float2(0.f, 0.f);
  if (real) v = *reinterpret_cast<const float2*>(emb + (size_t)node * Dd + ln * 2);
  float t = v.x * v.x + v.y * v.y;
  #pragma unroll
  for (int off = 32; off > 0; off >>= 1) t += __shfl_xor(t, off);

  const float E = fmaxf(sqrtf(t), EPSF);
  const float a = atanhf(fminf(E, MAXT));
  const float s = a / E;
  const float m2s = -2.f * s;

  const int tt = local >> 7, nd = local & 127;
  ushort2 w; w.x = f2bf(m2s * v.x); w.y = f2bf(m2s * v.y);
  char* dst = reinterpret_cast<char*>(embsw)
            + ((size_t)((chunk * TIL8 + tt) * NT + nd) << 8)
            + ((ln * 4) ^ ((nd & 7) << 4));
  *reinterpret_cast<ushort2*>(dst) = w;

  if (ln == 0) cpad[p] = real ? s * s * t : 3.0e38f;
}

// ---------------------------------------------------------------------------
// FAST PATH topk: transposed bf16-MFMA score GEMM + per-lane top-5.
// Block = 32 query rows x 12500-node chunk; 8 waves, wave owns 16 nodes/tile.
// D[node][q] = c_n + dot(emb'_n, z_q) = c_n - 2 s_n <emb_n, z_q> = score.
__global__ __launch_bounds__(512, 4) void k_topk8(
    const ushort* __restrict__ ztb, const ushort* __restrict__ embsw,
    const float* __restrict__ cpad, float* __restrict__ candV,
    int* __restrict__ candI)
{
  __shared__ __align__(16) ushort Bsm[2][NT * Dd];   // 2 x 32KB swizzled emb' tiles
  __shared__ __align__(16) float cb[2][NT];          // c_n per tile

  const int tid = threadIdx.x;
  const int ln = tid & 63;
  const int wv = tid >> 6;       // 0..7 : node sub-tile (16 nodes)
  const int ln15 = ln & 15;
  const int g = ln >> 4;         // 0..3
  const int qBase = blockIdx.x * RQ;
  const int chunk = blockIdx.y;
  const char* embc = reinterpret_cast<const char*>(embsw)
                   + (size_t)chunk * (TIL8 * TILE_BYTES);
  const float* cch = cpad + (size_t)chunk * PAD8;

  // B operand: z fragments for 32 q-rows, loaded once, reused all 98 tiles.
  // lane supplies z[q = 16f + ln15][k = 32ks + 8g .. +8]
  short8v zfr[2][4];
  #pragma unroll
  for (int f = 0; f < 2; ++f)
    #pragma unroll
    for (int ks = 0; ks < 4; ++ks)
      zfr[f][ks] = *reinterpret_cast<const short8v*>(
          ztb + (size_t)(qBase + 16 * f + ln15) * Dd + 32 * ks + 8 * g);

  // A operand LDS byte offsets (swizzled): node = wv*16 + ln15, k = 32ks + 8g
  int rdoff[4];
  #pragma unroll
  for (int ks = 0; ks < 4; ++ks)
    rdoff[ks] = (wv * 16 + ln15) * 256 + ((ks * 64 + g * 16) ^ ((ln15 & 7) << 4));
  const int coff = wv * 64 + g * 16;   // byte offset of this lane's 4 c values

  float tv[2][5]; int ti[2][5];
  #pragma unroll
  for (int f = 0; f < 2; ++f)
    #pragma unroll
    for (int q = 0; q < 5; ++q) { tv[f][q] = 3.0e38f; ti[f][q] = 0x7fffffff; }

  auto stage = [&](int t, int buf) {
    const char* src = embc + (size_t)t * TILE_BYTES + tid * 16;
    char* lb = reinterpret_cast<char*>(&Bsm[buf][0]) + tid * 16;
    #pragma unroll
    for (int i = 0; i < 4; ++i) {
      __builtin_amdgcn_global_load_lds(
          (const __attribute__((address_space(1))) unsigned int*)(src + i * 8192),
          (__attribute__((address_space(3))) unsigned int*)(lb + i * 8192),
          16, 0, 0);
    }
    if (tid < NT) {
      __builtin_amdgcn_global_load_lds(
          (const __attribute__((address_space(1))) unsigned int*)(cch + t * NT + tid),
          (__attribute__((address_space(3))) unsigned int*)(&cb[buf][tid]),
          4, 0, 0);
    }
  };

  stage(0, 0);
  __syncthreads();

  // node id of this lane's i=0 slot for tile 0
  int nb = chunk * CH8 + wv * 16 + 4 * g;

  for (int t = 0; t < TIL8; ++t) {
    const int buf = t & 1;
    if (t + 1 < TIL8) stage(t + 1, buf ^ 1);   // prefetch; drained at barrier

    const char* bbase = reinterpret_cast<const char*>(&Bsm[buf][0]);
    short8v ae[4];
    #pragma unroll
    for (int ks = 0; ks < 4; ++ks)
      ae[ks] = *reinterpret_cast<const short8v*>(bbase + rdoff[ks]);
    const f32x4 cinit = *reinterpret_cast<const f32x4*>(
        reinterpret_cast<const char*>(&cb[buf][0]) + coff);

    f32x4 a0 = __builtin_amdgcn_mfma_f32_16x16x32_bf16(ae[0], zfr[0][0], cinit, 0, 0, 0);
    f32x4 a1 = __builtin_amdgcn_mfma_f32_16x16x32_bf16(ae[0], zfr[1][0], cinit, 0, 0, 0);
    #pragma unroll
    for (int ks = 1; ks < 4; ++ks) {
      a0 = __builtin_amdgcn_mfma_f32_16x16x32_bf16(ae[ks], zfr[0][ks], a0, 0, 0, 0);
      a1 = __builtin_amdgcn_mfma_f32_16x16x32_bf16(ae[ks], zfr[1][ks], a1, 0, 0, 0);
    }

    // epilogue: 8 inserts (2 q-rows x 4 nodes); pad scores are +INF, never win
    #pragma unroll
    for (int i = 0; i < 4; ++i) {
      INS5(tv[0], ti[0], a0[i], nb + i);
      INS5(tv[1], ti[1], a1[i], nb + i);
    }
    nb += NT;
    __syncthreads();
  }

  // merge the 4 g-groups per (q, wave): butterfly over lanes ln^16, ln^32
  #pragma unroll
  for (int m = 16; m <= 32; m <<= 1) {
    #pragma unroll
    for (int f = 0; f < 2; ++f) {
      float ov[5]; int oi[5];
      #pragma unroll
      for (int q = 0; q < 5; ++q) {
        ov[q] = __shfl_xor(tv[f][q], m);
        oi[q] = __shfl_xor(ti[f][q], m);
      }
      #pragma unroll
      for (int q = 0; q < 5; ++q) INS5L(tv[f], ti[f], ov[q], oi[q]);
    }
  }
  // cross-wave merge via reused LDS (loop-end barrier already passed)
  float* mgv = reinterpret_cast<float*>(&Bsm[0][0]);              // [32][8][5]
  int* mgi = reinterpret_cast<int*>(
      reinterpret_cast<char*>(&Bsm[0][0]) + RQ * 8 * Kk * 4);
  if (ln < 16) {
    #pragma unroll
    for (int f = 0; f < 2; ++f)
      #pragma unroll
      for (int q = 0; q < 5; ++q) {
        mgv[((16 * f + ln) * 8 + wv) * Kk + q] = tv[f][q];
        mgi[((16 * f + ln) * 8 + wv) * Kk + q] = ti[f][q];
      }
  }
  __syncthreads();
  if (tid < RQ) {
    float mv[5]; int mi[5];
    #pragma unroll
    for (int q = 0; q < 5; ++q) { mv[q] = mgv[(tid * 8 + 0) * Kk + q]; mi[q] = mgi[(tid * 8 + 0) * Kk + q]; }
    for (int w = 1; w < 8; ++w)
      #pragma unroll
      for (int q = 0; q < 5; ++q)
        INS5L(mv, mi, mgv[(tid * 8 + w) * Kk + q], mgi[(tid * 8 + w) * Kk + q]);
    const size_t o = ((size_t)(qBase + tid) * NCH8 + chunk) * Kk;
    #pragma unroll
    for (int q = 0; q < 5; ++q) { candV[o + q] = mv[q]; candI[o + q] = mi[q]; }
  }
}

// ---------------------------------------------------------------------------
// LEGACY PATH (round-3, verified): per-node scalars + in-loop cvt staging.
__global__ __launch_bounds__(256) void k_node(
    const float* __restrict__ emb, float* __restrict__ sArr, float* __restrict__ cArr)
{
  const int wv = threadIdx.x >> 6, ln = threadIdx.x & 63;
  const int node = blockIdx.x * 4 + wv;
  const float2 v = *reinterpret_cast<const float2*>(emb + (size_t)node * Dd + ln * 2);
  float t = v.x * v.x + v.y * v.y;
  #pragma unroll
  for (int off = 32; off > 0; off >>= 1) t += __shfl_xor(t, off);
  if (ln == 0) {
    const float E = fmaxf(sqrtf(t), EPSF);
    const float a = atanhf(fminf(E, MAXT));
    const float s = a / E;
    sArr[node] = s;
    cArr[node] = s * s * t;
  }
}

__global__ __launch_bounds__(512, 2) void k_topk16(
    const ushort* __restrict__ ztb, const float* __restrict__ emb,
    const float* __restrict__ sArr, const float* __restrict__ cArr,
    float* __restrict__ candV, int* __restrict__ candI)
{
  __shared__ __align__(16) ushort Bsm[2][NT * Dd];
  __shared__ __align__(16) float2 sclb[2][NT];
  __shared__ __align__(16) float mgv[RT][2][Kk];
  __shared__ int mgi[RT][2][Kk];

  const int tid = threadIdx.x;
  const int ln = tid & 63;
  const int wv = tid >> 6;
  const int ln15 = ln & 15;
  const int g = ln >> 4;
  const int wr = wv >> 1;
  const int wc = wv & 1;
  const int rowBase = blockIdx.x * RT;
  const int chunkStart = blockIdx.y * CH16;

  short8v afr[2][4];
  #pragma unroll
  for (int f = 0; f < 2; ++f)
    #pragma unroll
    for (int ks = 0; ks < 4; ++ks)
      afr[f][ks] = *reinterpret_cast<const short8v*>(
          ztb + (size_t)(rowBase + 32 * wr + 16 * f + ln15) * Dd + 32 * ks + 8 * g);

  int rdoff[4];
  #pragma unroll
  for (int ks = 0; ks < 4; ++ks)
    rdoff[ks] = (wc * 64 + ln15) * 256 + ((g * 16 + ks * 64) ^ ((ln15 & 7) << 4));

  f32x4 acc[2][4];
  #pragma unroll
  for (int f = 0; f < 2; ++f)
    #pragma unroll
    for (int c = 0; c < 4; ++c) acc[f][c] = (f32x4)0.f;

  float tv[8][5]; int ti[8][5];
  #pragma unroll
  for (int r = 0; r < 8; ++r)
    #pragma unroll
    for (int q = 0; q < 5; ++q) { tv[r][q] = 3.0e38f; ti[r][q] = 0x7fffffff; }

  float4 ld[8];

  auto stageLoad = [&](int t) {
    const int tStart = t * NT;
    const int left = CH16 - tStart;
    #pragma unroll
    for (int i = 0; i < 8; ++i) {
      const int flat = i * 512 + tid;
      const int nd = flat >> 5;
      float4 v = make_float4(0.f, 0.f, 0.f, 0.f);
      if (nd < left)
        v = *reinterpret_cast<const float4*>(
            emb + (size_t)(chunkStart + tStart + nd) * Dd + (flat & 31) * 4);
      ld[i] = v;
    }
  };

  auto stageWrite = [&](int t, int buf) {
    char* base = reinterpret_cast<char*>(&Bsm[buf][0]);
    #pragma unroll
    for (int i = 0; i < 8; ++i) {
      const int flat = i * 512 + tid;
      const int nd = flat >> 5;
      const int kb = (flat & 31) * 8;
      ushort4 w;
      w.x = f2bf(ld[i].x); w.y = f2bf(ld[i].y);
      w.z = f2bf(ld[i].z); w.w = f2bf(ld[i].w);
      *reinterpret_cast<ushort4*>(base + nd * 256 + (kb ^ ((nd & 7) << 4))) = w;
    }
    const int tStart = t * NT;
    const int left = CH16 - tStart;
    if (tid < NT) {
      const bool ok = tid < left;
      sclb[buf][tid] = make_float2(ok ? -2.f * sArr[chunkStart + tStart + tid] : 0.f,
                                   ok ? cArr[chunkStart + tStart + tid] : 3.0e38f);
    }
  };

  stageLoad(0);
  stageWrite(0, 0);
  __syncthreads();

  for (int t = 0; t < TIL16; ++t) {
    const int buf = t & 1;
    const bool have = (t + 1) < TIL16;
    if (have) stageLoad(t + 1);

    const char* bbase = reinterpret_cast<const char*>(&Bsm[buf][0]);
    #pragma unroll
    for (int c = 0; c < 4; ++c) {
      #pragma unroll
      for (int ks = 0; ks < 4; ++ks) {
        const short8v bfr = *reinterpret_cast<const short8v*>(bbase + c * 4096 + rdoff[ks]);
        acc[0][c] = __builtin_amdgcn_mfma_f32_16x16x32_bf16(afr[0][ks], bfr, acc[0][c], 0, 0, 0);
        acc[1][c] = __builtin_amdgcn_mfma_f32_16x16x32_bf16(afr[1][ks], bfr, acc[1][c], 0, 0, 0);
      }
    }

    if (have) stageWrite(t + 1, buf ^ 1);

    #pragma unroll
    for (int c = 0; c < 4; ++c) {
      const int nl = wc * 64 + c * 16 + ln15;
      const float2 sc2 = sclb[buf][nl];
      const int node = chunkStart + t * NT + nl;
      #pragma unroll
      for (int f = 0; f < 2; ++f) {
        #pragma unroll
        for (int i = 0; i < 4; ++i) {
          const float v = fmaf(sc2.x, acc[f][c][i], sc2.y);
          INS5(tv[f * 4 + i], ti[f * 4 + i], v, node);
        }
        acc[f][c] = (f32x4)0.f;
      }
    }
    __syncthreads();
  }

  #pragma unroll
  for (int m = 1; m <= 8; m <<= 1) {
    #pragma unroll
    for (int r = 0; r < 8; ++r) {
      float ov[5]; int oi[5];
      #pragma unroll
      for (int q = 0; q < 5; ++q) {
        ov[q] = __shfl_xor(tv[r][q], m);
        oi[q] = __shfl_xor(ti[r][q], m);
      }
      #pragma unroll
      for (int q = 0; q < 5; ++q) INS5L(tv[r], ti[r], ov[q], oi[q]);
    }
  }
  if (ln15 == 0) {
    #pragma unroll
    for (int f = 0; f < 2; ++f)
      #pragma unroll
      for (int i = 0; i < 4; ++i) {
        const int row = 32 * wr + 16 * f + 4 * g + i;
        #pragma unroll
        for (int q = 0; q < 5; ++q) {
          mgv[row][wc][q] = tv[f * 4 + i][q];
          mgi[row][wc][q] = ti[f * 4 + i][q];
        }
      }
  }
  __syncthreads();
  if (tid < RT) {
    float mv[5]; int mi[5];
    #pragma unroll
    for (int q = 0; q < 5; ++q) { mv[q] = mgv[tid][0][q]; mi[q] = mgi[tid][0][q]; }
    #pragma unroll
    for (int q = 0; q < 5; ++q) INS5L(mv, mi, mgv[tid][1][q], mgi[tid][1][q]);
    const size_t o = ((size_t)(rowBase + tid) * NCH16 + blockIdx.y) * Kk;
    #pragma unroll
    for (int q = 0; q < 5; ++q) { candV[o + q] = mv[q]; candI[o + q] = mi[q]; }
  }
}

// ---------------------------------------------------------------------------
// Kernel 4 (shared): wave-parallel final merge -> gather-mean -> mobius_add.
__global__ __launch_bounds__(128) void k_fuse(
    const float* __restrict__ emb, const float* __restrict__ candV,
    const int* __restrict__ candI, const float* __restrict__ zhyp,
    float* __restrict__ out, int ncand)
{
  __shared__ int sidx[Kk];
  __shared__ float red[6];
  const int row = blockIdx.x;
  const int tid = threadIdx.x;
  if (tid < 64) {
    float mv[5]; int mi[5];
    #pragma unroll
    for (int q = 0; q < 5; ++q) { mv[q] = 3.0e38f; mi[q] = 0x7fffffff; }
    const size_t base = (size_t)row * ncand;
    for (int j = tid; j < ncand; j += 64) INS5L(mv, mi, candV[base + j], candI[base + j]);
    #pragma unroll
    for (int m = 1; m <= 32; m <<= 1) {
      float ov[5]; int oi[5];
      #pragma unroll
      for (int q = 0; q < 5; ++q) { ov[q] = __shfl_xor(mv[q], m); oi[q] = __shfl_xor(mi[q], m); }
      #pragma unroll
      for (int q = 0; q < 5; ++q) INS5L(mv, mi, ov[q], oi[q]);
    }
    if (tid == 0) {
      #pragma unroll
      for (int q = 0; q < 5; ++q) sidx[q] = mi[q];
    }
  }
  __syncthreads();
  float y = 0.f;
  #pragma unroll
  for (int q = 0; q < Kk; ++q) y += emb[(size_t)sidx[q] * Dd + tid];
  y = y / 5.0f;
  const float x = zhyp[(size_t)row * Dd + tid];
  float x2 = x * x, y2 = y * y, xy = x * y;
  #pragma unroll
  for (int off = 32; off > 0; off >>= 1) {
    x2 += __shfl_xor(x2, off);
    y2 += __shfl_xor(y2, off);
    xy += __shfl_xor(xy, off);
  }
  const int wv = tid >> 6, ln = tid & 63;
  if (ln == 0) { red[wv * 3 + 0] = x2; red[wv * 3 + 1] = y2; red[wv * 3 + 2] = xy; }
  __syncthreads();
  x2 = red[0] + red[3]; y2 = red[1] + red[4]; xy = red[2] + red[5];
  const float num = (1.f + 2.f * xy + y2) * x + (1.f - x2) * y;
  const float den = 1.f + 2.f * xy + x2 * y2;
  out[(size_t)row * Dd + tid] = num / (den + EPSF);
}

// ---------------------------------------------------------------------------
extern "C" void kernel_launch(void* const* d_in, const int* in_sizes, int n_in,
                              void* d_out, int out_size, void* d_ws, size_t ws_size,
                              hipStream_t stream)
{
  (void)in_sizes; (void)n_in; (void)out_size;
  const float* zseq = (const float*)d_in[0];
  const float* emb  = (const float*)d_in[1];
  const float* W    = (const float*)d_in[2];
  const float* bias = (const float*)d_in[3];
  float* out = (float*)d_out;            // [z_fused (B*D) | z_hyp (B*D)] f32

  const size_t ztbBytes   = (size_t)Bb * Dd * 2;                  // 524288
  const size_t embswBytes = (size_t)NCH8 * TIL8 * TILE_BYTES;     // 25690112
  const size_t cpadBytes  = (size_t)NCH8 * PAD8 * 4;              // 401408
  const size_t candVBytes = (size_t)Bb * NCH8 * Kk * 4;           // 327680
  const size_t needFast = ztbBytes + embswBytes + cpadBytes + 2 * candVBytes;

  hipLaunchKernelGGL(k_proj, dim3(Bb / 8), dim3(128), 0, stream,
                     zseq, W, bias, out + HALF, (ushort*)d_ws);

  if (ws_size >= needFast) {
    char* ws = (char*)d_ws;
    ushort* ztb   = (ushort*)ws;
    ushort* embsw = (ushort*)(ws + ztbBytes);
    float*  cpad  = (float*)(ws + ztbBytes + embswBytes);
    float*  candV = (float*)(ws + ztbBytes + embswBytes + cpadBytes);
    int*    candI = (int*)(ws + ztbBytes + embswBytes + cpadBytes + candVBytes);

    hipLaunchKernelGGL(k_pack, dim3(NCH8 * PAD8 / 4), dim3(256), 0, stream,
                       emb, embsw, cpad);
    hipLaunchKernelGGL(k_topk8, dim3(Bb / RQ, NCH8), dim3(512), 0, stream,
                       ztb, embsw, cpad, candV, candI);
    hipLaunchKernelGGL(k_fuse, dim3(Bb), dim3(128), 0, stream,
                       emb, candV, candI, out + HALF, out, NCH8 * Kk);
  } else {
    char* ws = (char*)d_ws;
    ushort* ztb  = (ushort*)ws;
    float* sArr  = (float*)(ws + ztbBytes);
    float* cArr  = sArr + Nn;
    float* candV = cArr + Nn;
    int*   candI = (int*)(candV + (size_t)Bb * NCH16 * Kk);

    hipLaunchKernelGGL(k_node, dim3(Nn / 4), dim3(256), 0, stream, emb, sArr, cArr);
    hipLaunchKernelGGL(k_topk16, dim3(Bb / RT, NCH16), dim3(512), 0, stream,
                       ztb, emb, sArr, cArr, candV, candI);
    hipLaunchKernelGGL(k_fuse, dim3(Bb), dim3(128), 0, stream,
                       emb, candV, candI, out + HALF, out, NCH16 * Kk);
  }
}

// Round 6
// 218.123 us; speedup vs baseline: 1.9428x; 1.3666x over previous
//
#include <hip/hip_runtime.h>
#include <hip/hip_bf16.h>
#include <math.h>

#define EPSF 1e-7f
#define MAXT 0.99999f   // 1 - 1e-5

typedef __attribute__((ext_vector_type(8))) short short8v;   // 8 x bf16 (4 VGPR)
typedef __attribute__((ext_vector_type(4))) float f32x4;     // MFMA C/D frag

constexpr int Bb = 2048;
constexpr int Ss = 768;
constexpr int Dd = 128;
constexpr int Nn = 100000;
constexpr int Kk = 5;
constexpr int HALF = Bb * Dd;        // 262144
constexpr int NT = 128;              // nodes per tile
constexpr int TILE_BYTES = NT * Dd * 2;  // 32768
constexpr float SBIAS = 16.0f;       // score-positivity bias (|2 s dot| < 12.5)

// fast path: transposed MFMA (A=emb', B=z), 8 chunks of 12500, 98 tiles/chunk
constexpr int NCH8 = 8;
constexpr int CH8 = Nn / NCH8;       // 12500
constexpr int TIL8 = 98;             // ceil(12500/128)
constexpr int PAD8 = TIL8 * NT;      // 12544 padded slots per chunk (fits 14 bits)
constexpr int RQ = 32;               // query rows per block

// legacy path (round-3, verified): 16 chunks of 6250, in-loop cvt staging
constexpr int NCH16 = 16;
constexpr int CH16 = Nn / NCH16;     // 6250
constexpr int TIL16 = (CH16 + NT - 1) / NT;  // 49
constexpr int RT = 128;

static __device__ __forceinline__ ushort f2bf(float x) {
  __hip_bfloat16 h = __float2bfloat16(x);
  return *reinterpret_cast<ushort*>(&h);
}

static __device__ __forceinline__ unsigned umn(unsigned a, unsigned b) { return a < b ? a : b; }
static __device__ __forceinline__ unsigned umx(unsigned a, unsigned b) { return a > b ? a : b; }

// Branchless insert of v into ascending sorted k[0..4], keeping 5 smallest.
// 9 VALU (4 max + 5 min), dataflow depth ~3, no cndmask/branches.
static __device__ __forceinline__ void ins5u(unsigned* k, unsigned v) {
  const unsigned x1 = umx(k[0], v);
  const unsigned x2 = umx(k[1], v);
  const unsigned x3 = umx(k[2], v);
  const unsigned x4 = umx(k[3], v);
  k[0] = umn(k[0], v);
  k[1] = umn(k[1], x1);
  k[2] = umn(k[2], x2);
  k[3] = umn(k[3], x3);
  k[4] = umn(k[4], x4);
}

// Insert into ascending-sorted top-5 (value,index) — legacy path only.
#define INS5(TV, TI, V, ID) do { \
  const float _v = (V); const int _id = (ID); \
  if (_v < TV[4]) { \
    TV[4] = _v; TI[4] = _id; \
    if (TV[4] < TV[3]) { float _t=TV[3];TV[3]=TV[4];TV[4]=_t;int _u=TI[3];TI[3]=TI[4];TI[4]=_u; } \
    if (TV[3] < TV[2]) { float _t=TV[2];TV[2]=TV[3];TV[3]=_t;int _u=TI[2];TI[2]=TI[3];TI[3]=_u; } \
    if (TV[2] < TV[1]) { float _t=TV[1];TV[1]=TV[2];TV[2]=_t;int _u=TI[1];TI[1]=TI[2];TI[2]=_u; } \
    if (TV[1] < TV[0]) { float _t=TV[0];TV[0]=TV[1];TV[1]=_t;int _u=TI[0];TI[0]=TI[1];TI[1]=_u; } \
  } } while(0)

// Lexicographic (value, index) insert for merging unordered candidate streams.
#define LXLT(V,I,V2,I2) ((V) < (V2) || ((V) == (V2) && (I) < (I2)))
#define INS5L(TV, TI, V, ID) do { \
  const float _v = (V); const int _id = (ID); \
  if (LXLT(_v,_id,TV[4],TI[4])) { \
    TV[4]=_v; TI[4]=_id; \
    if (LXLT(TV[4],TI[4],TV[3],TI[3])) { float _t=TV[3];TV[3]=TV[4];TV[4]=_t;int _u=TI[3];TI[3]=TI[4];TI[4]=_u; } \
    if (LXLT(TV[3],TI[3],TV[2],TI[2])) { float _t=TV[2];TV[2]=TV[3];TV[3]=_t;int _u=TI[2];TI[2]=TI[3];TI[3]=_u; } \
    if (LXLT(TV[2],TI[2],TV[1],TI[1])) { float _t=TV[1];TV[1]=TV[2];TV[2]=_t;int _u=TI[1];TI[1]=TI[2];TI[2]=_u; } \
    if (LXLT(TV[1],TI[1],TV[0],TI[0])) { float _t=TV[0];TV[0]=TV[1];TV[1]=_t;int _u=TI[0];TI[0]=TI[1];TI[1]=_u; } \
  } } while(0)

// ---------------------------------------------------------------------------
// Kernel 1 (shared): z_proj = z_seq @ W.T + b; z_hyp = expmap0 -> out[HALF..];
// z_tan = logmap0(z_hyp) -> ztb (bf16). 8 rows/block, 128 threads.
__global__ __launch_bounds__(128) void k_proj(
    const float* __restrict__ zseq, const float* __restrict__ W,
    const float* __restrict__ bias, float* __restrict__ outH,
    ushort* __restrict__ ztb)
{
  __shared__ __align__(16) float zrow[8][768];
  __shared__ float zp[8][128];
  __shared__ float rno[8];
  const int tid = threadIdx.x;
  const int r0 = blockIdx.x * 8;

  {
    const float4* src = reinterpret_cast<const float4*>(zseq + (size_t)r0 * Ss);
    float4* dst = reinterpret_cast<float4*>(&zrow[0][0]);
    #pragma unroll
    for (int i = 0; i < 12; ++i) dst[i * 128 + tid] = src[i * 128 + tid];
  }
  __syncthreads();

  float acc[8];
  const float bv = bias[tid];
  #pragma unroll
  for (int r = 0; r < 8; ++r) acc[r] = bv;
  const float4* w4 = reinterpret_cast<const float4*>(W + (size_t)tid * Ss);
  for (int j = 0; j < Ss / 4; ++j) {
    const float4 w = w4[j];
    #pragma unroll
    for (int r = 0; r < 8; ++r) {
      const float4 z = *reinterpret_cast<const float4*>(&zrow[r][j * 4]);
      acc[r] = fmaf(z.x, w.x, acc[r]);
      acc[r] = fmaf(z.y, w.y, acc[r]);
      acc[r] = fmaf(z.z, w.z, acc[r]);
      acc[r] = fmaf(z.w, w.w, acc[r]);
    }
  }
  #pragma unroll
  for (int r = 0; r < 8; ++r) zp[r][tid] = acc[r];
  __syncthreads();

  const int wv = tid >> 6, ln = tid & 63;
  #pragma unroll
  for (int rr = 0; rr < 4; ++rr) {
    const int r = wv * 4 + rr;
    float v = zp[r][ln] * zp[r][ln] + zp[r][ln + 64] * zp[r][ln + 64];
    #pragma unroll
    for (int off = 32; off > 0; off >>= 1) v += __shfl_xor(v, off);
    if (ln == 0) rno[r] = v;
  }
  __syncthreads();

  #pragma unroll
  for (int r = 0; r < 8; ++r) {
    const float n = fmaxf(sqrtf(rno[r]), EPSF);
    const float zh = tanhf(n) * zp[r][tid] / n;
    outH[(size_t)(r0 + r) * Dd + tid] = zh;   // z_hyp output (f32)
    zp[r][tid] = zh;
  }
  __syncthreads();
  #pragma unroll
  for (int rr = 0; rr < 4; ++rr) {
    const int r = wv * 4 + rr;
    float v = zp[r][ln] * zp[r][ln] + zp[r][ln + 64] * zp[r][ln + 64];
    #pragma unroll
    for (int off = 32; off > 0; off >>= 1) v += __shfl_xor(v, off);
    if (ln == 0) rno[r] = v;
  }
  __syncthreads();
  #pragma unroll
  for (int r = 0; r < 8; ++r) {
    const float m = fmaxf(sqrtf(rno[r]), EPSF);
    const float a = atanhf(fminf(m, MAXT));
    ztb[(size_t)(r0 + r) * Dd + tid] = f2bf(a * zp[r][tid] / m);
  }
}

// ---------------------------------------------------------------------------
// FAST PATH pack: emb' = bf16(-2*s_n*emb_n) pre-swizzled in tiled LDS image;
// cpad[slot] = c_n + SBIAS (score made positive => asuint is monotone), or
// +INF for pad slots. One wave per padded slot.
__global__ __launch_bounds__(256) void k_pack(
    const float* __restrict__ emb, ushort* __restrict__ embsw,
    float* __restrict__ cpad)
{
  const int wv = threadIdx.x >> 6, ln = threadIdx.x & 63;
  const int p = blockIdx.x * 4 + wv;          // padded slot
  const int chunk = p / PAD8;
  const int local = p - chunk * PAD8;
  const bool real = local < CH8;
  const int node = chunk * CH8 + local;
  float2 v = make_float2(0.f, 0.f);
  if (real) v = *reinterpret_cast<const float2*>(emb + (size_t)node * Dd + ln * 2);
  float t = v.x * v.x + v.y * v.y;
  #pragma unroll
  for (int off = 32; off > 0; off >>= 1) t += __shfl_xor(t, off);

  const float E = fmaxf(sqrtf(t), EPSF);
  const float a = atanhf(fminf(E, MAXT));
  const float s = a / E;
  const float m2s = -2.f * s;

  const int tt = local >> 7, nd = local & 127;
  ushort2 w; w.x = f2bf(m2s * v.x); w.y = f2bf(m2s * v.y);
  char* dst = reinterpret_cast<char*>(embsw)
            + ((size_t)((chunk * TIL8 + tt) * NT + nd) << 8)
            + ((ln * 4) ^ ((nd & 7) << 4));
  *reinterpret_cast<ushort2*>(dst) = w;

  if (ln == 0) cpad[p] = real ? (s * s * t + SBIAS) : 3.0e38f;
}

// ---------------------------------------------------------------------------
// FAST PATH topk: transposed bf16-MFMA score GEMM + packed-key top-5.
// Block = 32 query rows x 12500-node chunk; 8 waves, wave owns 16 nodes/tile.
// acc[node][q] = (c_n + SBIAS) + dot(emb'_n, z_q) = biased score (positive).
// key = (asuint(score) & 0xFFFFC000) | local_idx : u32 order == (score, idx).
__global__ __launch_bounds__(512, 4) void k_topk8(
    const ushort* __restrict__ ztb, const ushort* __restrict__ embsw,
    const float* __restrict__ cpad, float* __restrict__ candV,
    int* __restrict__ candI)
{
  __shared__ __align__(16) ushort Bsm[2][NT * Dd];   // 2 x 32KB swizzled emb' tiles
  __shared__ __align__(16) float cb[2][NT];          // biased c_n per tile

  const int tid = threadIdx.x;
  const int ln = tid & 63;
  const int wv = tid >> 6;       // 0..7 : node sub-tile (16 nodes)
  const int ln15 = ln & 15;
  const int g = ln >> 4;         // 0..3
  const int qBase = blockIdx.x * RQ;
  const int chunk = blockIdx.y;
  const char* embc = reinterpret_cast<const char*>(embsw)
                   + (size_t)chunk * (TIL8 * TILE_BYTES);
  const float* cch = cpad + (size_t)chunk * PAD8;

  // B operand: z fragments for 32 q-rows, loaded once, reused all 98 tiles.
  short8v zfr[2][4];
  #pragma unroll
  for (int f = 0; f < 2; ++f)
    #pragma unroll
    for (int ks = 0; ks < 4; ++ks)
      zfr[f][ks] = *reinterpret_cast<const short8v*>(
          ztb + (size_t)(qBase + 16 * f + ln15) * Dd + 32 * ks + 8 * g);

  // A operand LDS byte offsets (swizzled): node = wv*16 + ln15, k = 32ks + 8g
  int rdoff[4];
  #pragma unroll
  for (int ks = 0; ks < 4; ++ks)
    rdoff[ks] = (wv * 16 + ln15) * 256 + ((ks * 64 + g * 16) ^ ((ln15 & 7) << 4));
  const int coff = wv * 64 + g * 16;   // byte offset of this lane's 4 c values

  unsigned tv0[5], tv1[5];
  #pragma unroll
  for (int q = 0; q < 5; ++q) { tv0[q] = 0xFFFFFFFFu; tv1[q] = 0xFFFFFFFFu; }

  auto stage = [&](int t, int buf) {
    const char* src = embc + (size_t)t * TILE_BYTES + tid * 16;
    char* lb = reinterpret_cast<char*>(&Bsm[buf][0]) + tid * 16;
    #pragma unroll
    for (int i = 0; i < 4; ++i) {
      __builtin_amdgcn_global_load_lds(
          (const __attribute__((address_space(1))) unsigned int*)(src + i * 8192),
          (__attribute__((address_space(3))) unsigned int*)(lb + i * 8192),
          16, 0, 0);
    }
    if (tid < NT) {
      __builtin_amdgcn_global_load_lds(
          (const __attribute__((address_space(1))) unsigned int*)(cch + t * NT + tid),
          (__attribute__((address_space(3))) unsigned int*)(&cb[buf][tid]),
          4, 0, 0);
    }
  };

  stage(0, 0);
  __syncthreads();

  for (int t = 0; t < TIL8; ++t) {
    const int buf = t & 1;
    if (t + 1 < TIL8) stage(t + 1, buf ^ 1);   // prefetch; drained at barrier

    const char* bbase = reinterpret_cast<const char*>(&Bsm[buf][0]);
    short8v ae[4];
    #pragma unroll
    for (int ks = 0; ks < 4; ++ks)
      ae[ks] = *reinterpret_cast<const short8v*>(bbase + rdoff[ks]);
    const f32x4 cinit = *reinterpret_cast<const f32x4*>(
        reinterpret_cast<const char*>(&cb[buf][0]) + coff);

    f32x4 a0 = __builtin_amdgcn_mfma_f32_16x16x32_bf16(ae[0], zfr[0][0], cinit, 0, 0, 0);
    f32x4 a1 = __builtin_amdgcn_mfma_f32_16x16x32_bf16(ae[0], zfr[1][0], cinit, 0, 0, 0);
    #pragma unroll
    for (int ks = 1; ks < 4; ++ks) {
      a0 = __builtin_amdgcn_mfma_f32_16x16x32_bf16(ae[ks], zfr[0][ks], a0, 0, 0, 0);
      a1 = __builtin_amdgcn_mfma_f32_16x16x32_bf16(ae[ks], zfr[1][ks], a1, 0, 0, 0);
    }

    // epilogue: pack keys (v_and_or) + branchless network insert. Pad slots
    // carry +3e38 biased scores -> huge keys, never selected.
    const unsigned ib = (unsigned)(t * NT + wv * 16 + 4 * g);
    #pragma unroll
    for (int i = 0; i < 4; ++i) {
      ins5u(tv0, (__float_as_uint(a0[i]) & 0xFFFFC000u) | (ib + i));
      ins5u(tv1, (__float_as_uint(a1[i]) & 0xFFFFC000u) | (ib + i));
    }
    __syncthreads();
  }

  // merge the 4 g-groups per (q, wave): butterfly over lanes ln^16, ln^32
  #pragma unroll
  for (int m = 16; m <= 32; m <<= 1) {
    unsigned ov[5];
    #pragma unroll
    for (int q = 0; q < 5; ++q) ov[q] = (unsigned)__shfl_xor((int)tv0[q], m);
    #pragma unroll
    for (int q = 0; q < 5; ++q) ins5u(tv0, ov[q]);
    #pragma unroll
    for (int q = 0; q < 5; ++q) ov[q] = (unsigned)__shfl_xor((int)tv1[q], m);
    #pragma unroll
    for (int q = 0; q < 5; ++q) ins5u(tv1, ov[q]);
  }
  // cross-wave merge via reused LDS (loop-end barrier already passed)
  unsigned* mgk = reinterpret_cast<unsigned*>(&Bsm[0][0]);        // [RQ][8][5]
  if (ln < 16) {
    #pragma unroll
    for (int q = 0; q < 5; ++q) {
      mgk[((0 + ln) * 8 + wv) * Kk + q] = tv0[q];
      mgk[((16 + ln) * 8 + wv) * Kk + q] = tv1[q];
    }
  }
  __syncthreads();
  if (tid < RQ) {
    unsigned mv[5];
    #pragma unroll
    for (int q = 0; q < 5; ++q) mv[q] = mgk[(tid * 8 + 0) * Kk + q];
    for (int w = 1; w < 8; ++w)
      #pragma unroll
      for (int q = 0; q < 5; ++q) ins5u(mv, mgk[(tid * 8 + w) * Kk + q]);
    // decode: truncated score float + global node index
    const size_t o = ((size_t)(qBase + tid) * NCH8 + chunk) * Kk;
    #pragma unroll
    for (int q = 0; q < 5; ++q) {
      candV[o + q] = __uint_as_float(mv[q] & 0xFFFFC000u);
      candI[o + q] = chunk * CH8 + (int)(mv[q] & 0x3FFFu);
    }
  }
}

// ---------------------------------------------------------------------------
// LEGACY PATH (round-3, verified): per-node scalars + in-loop cvt staging.
__global__ __launch_bounds__(256) void k_node(
    const float* __restrict__ emb, float* __restrict__ sArr, float* __restrict__ cArr)
{
  const int wv = threadIdx.x >> 6, ln = threadIdx.x & 63;
  const int node = blockIdx.x * 4 + wv;
  const float2 v = *reinterpret_cast<const float2*>(emb + (size_t)node * Dd + ln * 2);
  float t = v.x * v.x + v.y * v.y;
  #pragma unroll
  for (int off = 32; off > 0; off >>= 1) t += __shfl_xor(t, off);
  if (ln == 0) {
    const float E = fmaxf(sqrtf(t), EPSF);
    const float a = atanhf(fminf(E, MAXT));
    const float s = a / E;
    sArr[node] = s;
    cArr[node] = s * s * t;
  }
}

__global__ __launch_bounds__(512, 2) void k_topk16(
    const ushort* __restrict__ ztb, const float* __restrict__ emb,
    const float* __restrict__ sArr, const float* __restrict__ cArr,
    float* __restrict__ candV, int* __restrict__ candI)
{
  __shared__ __align__(16) ushort Bsm[2][NT * Dd];
  __shared__ __align__(16) float2 sclb[2][NT];
  __shared__ __align__(16) float mgv[RT][2][Kk];
  __shared__ int mgi[RT][2][Kk];

  const int tid = threadIdx.x;
  const int ln = tid & 63;
  const int wv = tid >> 6;
  const int ln15 = ln & 15;
  const int g = ln >> 4;
  const int wr = wv >> 1;
  const int wc = wv & 1;
  const int rowBase = blockIdx.x * RT;
  const int chunkStart = blockIdx.y * CH16;

  short8v afr[2][4];
  #pragma unroll
  for (int f = 0; f < 2; ++f)
    #pragma unroll
    for (int ks = 0; ks < 4; ++ks)
      afr[f][ks] = *reinterpret_cast<const short8v*>(
          ztb + (size_t)(rowBase + 32 * wr + 16 * f + ln15) * Dd + 32 * ks + 8 * g);

  int rdoff[4];
  #pragma unroll
  for (int ks = 0; ks < 4; ++ks)
    rdoff[ks] = (wc * 64 + ln15) * 256 + ((g * 16 + ks * 64) ^ ((ln15 & 7) << 4));

  f32x4 acc[2][4];
  #pragma unroll
  for (int f = 0; f < 2; ++f)
    #pragma unroll
    for (int c = 0; c < 4; ++c) acc[f][c] = (f32x4)0.f;

  float tv[8][5]; int ti[8][5];
  #pragma unroll
  for (int r = 0; r < 8; ++r)
    #pragma unroll
    for (int q = 0; q < 5; ++q) { tv[r][q] = 3.0e38f; ti[r][q] = 0x7fffffff; }

  float4 ld[8];

  auto stageLoad = [&](int t) {
    const int tStart = t * NT;
    const int left = CH16 - tStart;
    #pragma unroll
    for (int i = 0; i < 8; ++i) {
      const int flat = i * 512 + tid;
      const int nd = flat >> 5;
      float4 v = make_float4(0.f, 0.f, 0.f, 0.f);
      if (nd < left)
        v = *reinterpret_cast<const float4*>(
            emb + (size_t)(chunkStart + tStart + nd) * Dd + (flat & 31) * 4);
      ld[i] = v;
    }
  };

  auto stageWrite = [&](int t, int buf) {
    char* base = reinterpret_cast<char*>(&Bsm[buf][0]);
    #pragma unroll
    for (int i = 0; i < 8; ++i) {
      const int flat = i * 512 + tid;
      const int nd = flat >> 5;
      const int kb = (flat & 31) * 8;
      ushort4 w;
      w.x = f2bf(ld[i].x); w.y = f2bf(ld[i].y);
      w.z = f2bf(ld[i].z); w.w = f2bf(ld[i].w);
      *reinterpret_cast<ushort4*>(base + nd * 256 + (kb ^ ((nd & 7) << 4))) = w;
    }
    const int tStart = t * NT;
    const int left = CH16 - tStart;
    if (tid < NT) {
      const bool ok = tid < left;
      sclb[buf][tid] = make_float2(ok ? -2.f * sArr[chunkStart + tStart + tid] : 0.f,
                                   ok ? cArr[chunkStart + tStart + tid] : 3.0e38f);
    }
  };

  stageLoad(0);
  stageWrite(0, 0);
  __syncthreads();

  for (int t = 0; t < TIL16; ++t) {
    const int buf = t & 1;
    const bool have = (t + 1) < TIL16;
    if (have) stageLoad(t + 1);

    const char* bbase = reinterpret_cast<const char*>(&Bsm[buf][0]);
    #pragma unroll
    for (int c = 0; c < 4; ++c) {
      #pragma unroll
      for (int ks = 0; ks < 4; ++ks) {
        const short8v bfr = *reinterpret_cast<const short8v*>(bbase + c * 4096 + rdoff[ks]);
        acc[0][c] = __builtin_amdgcn_mfma_f32_16x16x32_bf16(afr[0][ks], bfr, acc[0][c], 0, 0, 0);
        acc[1][c] = __builtin_amdgcn_mfma_f32_16x16x32_bf16(afr[1][ks], bfr, acc[1][c], 0, 0, 0);
      }
    }

    if (have) stageWrite(t + 1, buf ^ 1);

    #pragma unroll
    for (int c = 0; c < 4; ++c) {
      const int nl = wc * 64 + c * 16 + ln15;
      const float2 sc2 = sclb[buf][nl];
      const int node = chunkStart + t * NT + nl;
      #pragma unroll
      for (int f = 0; f < 2; ++f) {
        #pragma unroll
        for (int i = 0; i < 4; ++i) {
          const float v = fmaf(sc2.x, acc[f][c][i], sc2.y);
          INS5(tv[f * 4 + i], ti[f * 4 + i], v, node);
        }
        acc[f][c] = (f32x4)0.f;
      }
    }
    __syncthreads();
  }

  #pragma unroll
  for (int m = 1; m <= 8; m <<= 1) {
    #pragma unroll
    for (int r = 0; r < 8; ++r) {
      float ov[5]; int oi[5];
      #pragma unroll
      for (int q = 0; q < 5; ++q) {
        ov[q] = __shfl_xor(tv[r][q], m);
        oi[q] = __shfl_xor(ti[r][q], m);
      }
      #pragma unroll
      for (int q = 0; q < 5; ++q) INS5L(tv[r], ti[r], ov[q], oi[q]);
    }
  }
  if (ln15 == 0) {
    #pragma unroll
    for (int f = 0; f < 2; ++f)
      #pragma unroll
      for (int i = 0; i < 4; ++i) {
        const int row = 32 * wr + 16 * f + 4 * g + i;
        #pragma unroll
        for (int q = 0; q < 5; ++q) {
          mgv[row][wc][q] = tv[f * 4 + i][q];
          mgi[row][wc][q] = ti[f * 4 + i][q];
        }
      }
  }
  __syncthreads();
  if (tid < RT) {
    float mv[5]; int mi[5];
    #pragma unroll
    for (int q = 0; q < 5; ++q) { mv[q] = mgv[tid][0][q]; mi[q] = mgi[tid][0][q]; }
    #pragma unroll
    for (int q = 0; q < 5; ++q) INS5L(mv, mi, mgv[tid][1][q], mgi[tid][1][q]);
    const size_t o = ((size_t)(rowBase + tid) * NCH16 + blockIdx.y) * Kk;
    #pragma unroll
    for (int q = 0; q < 5; ++q) { candV[o + q] = mv[q]; candI[o + q] = mi[q]; }
  }
}

// ---------------------------------------------------------------------------
// Kernel 4 (shared): wave-parallel final merge -> gather-mean -> mobius_add.
__global__ __launch_bounds__(128) void k_fuse(
    const float* __restrict__ emb, const float* __restrict__ candV,
    const int* __restrict__ candI, const float* __restrict__ zhyp,
    float* __restrict__ out, int ncand)
{
  __shared__ int sidx[Kk];
  __shared__ float red[6];
  const int row = blockIdx.x;
  const int tid = threadIdx.x;
  if (tid < 64) {
    float mv[5]; int mi[5];
    #pragma unroll
    for (int q = 0; q < 5; ++q) { mv[q] = 3.0e38f; mi[q] = 0x7fffffff; }
    const size_t base = (size_t)row * ncand;
    for (int j = tid; j < ncand; j += 64) INS5L(mv, mi, candV[base + j], candI[base + j]);
    #pragma unroll
    for (int m = 1; m <= 32; m <<= 1) {
      float ov[5]; int oi[5];
      #pragma unroll
      for (int q = 0; q < 5; ++q) { ov[q] = __shfl_xor(mv[q], m); oi[q] = __shfl_xor(mi[q], m); }
      #pragma unroll
      for (int q = 0; q < 5; ++q) INS5L(mv, mi, ov[q], oi[q]);
    }
    if (tid == 0) {
      #pragma unroll
      for (int q = 0; q < 5; ++q) sidx[q] = mi[q];
    }
  }
  __syncthreads();
  float y = 0.f;
  #pragma unroll
  for (int q = 0; q < Kk; ++q) y += emb[(size_t)sidx[q] * Dd + tid];
  y = y / 5.0f;
  const float x = zhyp[(size_t)row * Dd + tid];
  float x2 = x * x, y2 = y * y, xy = x * y;
  #pragma unroll
  for (int off = 32; off > 0; off >>= 1) {
    x2 += __shfl_xor(x2, off);
    y2 += __shfl_xor(y2, off);
    xy += __shfl_xor(xy, off);
  }
  const int wv = tid >> 6, ln = tid & 63;
  if (ln == 0) { red[wv * 3 + 0] = x2; red[wv * 3 + 1] = y2; red[wv * 3 + 2] = xy; }
  __syncthreads();
  x2 = red[0] + red[3]; y2 = red[1] + red[4]; xy = red[2] + red[5];
  const float num = (1.f + 2.f * xy + y2) * x + (1.f - x2) * y;
  const float den = 1.f + 2.f * xy + x2 * y2;
  out[(size_t)row * Dd + tid] = num / (den + EPSF);
}

// ---------------------------------------------------------------------------
extern "C" void kernel_launch(void* const* d_in, const int* in_sizes, int n_in,
                              void* d_out, int out_size, void* d_ws, size_t ws_size,
                              hipStream_t stream)
{
  (void)in_sizes; (void)n_in; (void)out_size;
  const float* zseq = (const float*)d_in[0];
  const float* emb  = (const float*)d_in[1];
  const float* W    = (const float*)d_in[2];
  const float* bias = (const float*)d_in[3];
  float* out = (float*)d_out;            // [z_fused (B*D) | z_hyp (B*D)] f32

  const size_t ztbBytes   = (size_t)Bb * Dd * 2;                  // 524288
  const size_t embswBytes = (size_t)NCH8 * TIL8 * TILE_BYTES;     // 25690112
  const size_t cpadBytes  = (size_t)NCH8 * PAD8 * 4;              // 401408
  const size_t candVBytes = (size_t)Bb * NCH8 * Kk * 4;           // 327680
  const size_t needFast = ztbBytes + embswBytes + cpadBytes + 2 * candVBytes;

  hipLaunchKernelGGL(k_proj, dim3(Bb / 8), dim3(128), 0, stream,
                     zseq, W, bias, out + HALF, (ushort*)d_ws);

  if (ws_size >= needFast) {
    char* ws = (char*)d_ws;
    ushort* ztb   = (ushort*)ws;
    ushort* embsw = (ushort*)(ws + ztbBytes);
    float*  cpad  = (float*)(ws + ztbBytes + embswBytes);
    float*  candV = (float*)(ws + ztbBytes + embswBytes + cpadBytes);
    int*    candI = (int*)(ws + ztbBytes + embswBytes + cpadBytes + candVBytes);

    hipLaunchKernelGGL(k_pack, dim3(NCH8 * PAD8 / 4), dim3(256), 0, stream,
                       emb, embsw, cpad);
    hipLaunchKernelGGL(k_topk8, dim3(Bb / RQ, NCH8), dim3(512), 0, stream,
                       ztb, embsw, cpad, candV, candI);
    hipLaunchKernelGGL(k_fuse, dim3(Bb), dim3(128), 0, stream,
                       emb, candV, candI, out + HALF, out, NCH8 * Kk);
  } else {
    char* ws = (char*)d_ws;
    ushort* ztb  = (ushort*)ws;
    float* sArr  = (float*)(ws + ztbBytes);
    float* cArr  = sArr + Nn;
    float* candV = cArr + Nn;
    int*   candI = (int*)(candV + (size_t)Bb * NCH16 * Kk);

    hipLaunchKernelGGL(k_node, dim3(Nn / 4), dim3(256), 0, stream, emb, sArr, cArr);
    hipLaunchKernelGGL(k_topk16, dim3(Bb / RT, NCH16), dim3(512), 0, stream,
                       ztb, emb, sArr, cArr, candV, candI);
    hipLaunchKernelGGL(k_fuse, dim3(Bb), dim3(128), 0, stream,
                       emb, candV, candI, out + HALF, out, NCH16 * Kk);
  }
}